// Round 3
// baseline (9455.655 us; speedup 1.0000x reference)
//
#include <hip/hip_runtime.h>
#include <cstdint>
#include <cstddef>

typedef unsigned short u16;
typedef unsigned int u32;
typedef __attribute__((ext_vector_type(8))) short short8;
typedef __attribute__((ext_vector_type(4))) float f32x4;

#define AGENT_SCOPE __HIP_MEMORY_SCOPE_AGENT
#define WG_SCOPE __HIP_MEMORY_SCOPE_WORKGROUP
#define SPIN_CAP 20000000
#define POLL_CAP 200000
#define SENT 0xFFFFFFFFu

__device__ __forceinline__ u16 f2bf(float f) {
  u32 u = __float_as_uint(f);
  return (u16)((u + 0x7FFFu + ((u >> 16) & 1u)) >> 16);
}
__device__ __forceinline__ float bf2f(u16 s) { return __uint_as_float(((u32)s) << 16); }
__device__ __forceinline__ float sigm(float x) { return 1.f / (1.f + __expf(-x)); }
__device__ __forceinline__ float tanha(float x) { return 1.f - 2.f / (__expf(2.f * x) + 1.f); }
__device__ __forceinline__ void wait_vm0() { asm volatile("s_waitcnt vmcnt(0)" ::: "memory"); }
__device__ __forceinline__ u32 um(u32 a, u32 b) { return a > b ? a : b; }

__device__ __forceinline__ short8 as_s8(uint4 v) {
  union { uint4 u; short8 s; } c; c.u = v; return c.s;
}
// cache-bypassing 16B loads (agent-visible); offset variants keep addr regs low
__device__ __forceinline__ uint4 ldx4_o0(const void* p) {
  uint4 r; asm volatile("global_load_dwordx4 %0, %1, off sc0 sc1" : "=v"(r) : "v"(p) : "memory"); return r;
}
__device__ __forceinline__ uint4 ldx4_o1(const void* p) {
  uint4 r; asm volatile("global_load_dwordx4 %0, %1, off offset:1024 sc0 sc1" : "=v"(r) : "v"(p) : "memory"); return r;
}
__device__ __forceinline__ uint4 ldx4_o2(const void* p) {
  uint4 r; asm volatile("global_load_dwordx4 %0, %1, off offset:2048 sc0 sc1" : "=v"(r) : "v"(p) : "memory"); return r;
}
__device__ __forceinline__ uint4 ldx4_o3(const void* p) {
  uint4 r; asm volatile("global_load_dwordx4 %0, %1, off offset:3072 sc0 sc1" : "=v"(r) : "v"(p) : "memory"); return r;
}

// Barrier-free, LDS-free hot loop. 256 WGs x 192 thr (3 waves):
//   wave0: L0 recurrence end-to-end (both gate col-tiles, act in-wave via shfl).
//   wave1: L1 fresh half (Wih1 . h0[s-1]) + partial merge + act/store h1.
//   wave2: L1 old half (Whh1 . h1[s-2]) -> LDS partials (stamped); decoder recon.
// Consumers poll MFMA A-fragments DIRECTLY from the LLC ring (fused detect +
// transfer, sentinel 0xFFFFFFFF = NaN-pair impossible for h in (-1,1)).
// Clears: 1 dw/lane of the slot reused next step, ordered before data stores by
// wait_vm0 in act. Guard dwords (1 load/lane) prove remote wave1 progress
// before wave0/wave1 clear slots still read by others (skip for s<2).
__global__ void __launch_bounds__(192, 1)
lstm_ae_kernel(const float* __restrict__ x,
    const float* __restrict__ eWih0, const float* __restrict__ eWhh0,
    const float* __restrict__ ebi0,  const float* __restrict__ ebh0,
    const float* __restrict__ eWih1, const float* __restrict__ eWhh1,
    const float* __restrict__ ebi1,  const float* __restrict__ ebh1,
    const float* __restrict__ dWhh0,
    const float* __restrict__ dbi0,  const float* __restrict__ dbh0,
    const float* __restrict__ dWih1, const float* __restrict__ dWhh1,
    const float* __restrict__ dbi1,  const float* __restrict__ dbh1,
    const float* __restrict__ tlW,   const float* __restrict__ tlb,
    const float* __restrict__ lhW,   const float* __restrict__ lhb,
    const float* __restrict__ opW,   const float* __restrict__ opb,
    float* __restrict__ out, char* __restrict__ wsb)
{
  __shared__ float sP2[2][2][256];               // [parity][tile][lane*4+r]
  __shared__ int sFlag[2];                       // stamp per parity
  __shared__ __align__(16) u16 sH1z[16 * 520];   // z-phase staging only
  __shared__ float sZ[16 * 64];

  u32* gcnt  = (u32*)wsb;
  float* zbuf= (float*)(wsb + 4096);             // [64][64] f32
  u32* h0r   = (u32*)(wsb + 32768);              // [3 q][4 col][64 rowg][64 dw]
  u32* h1r   = (u32*)(wsb + 229376);

  const int tid  = threadIdx.x;
  const int col  = blockIdx.x & 3;
  const int rowg = blockIdx.x >> 2;              // 0..63
  const int wid  = tid >> 6;
  const int lane = tid & 63;
  const int m    = lane & 15;
  const int q    = lane >> 4;
  const int qo   = q * 8;

  auto gwr = [&](int nl) { return ((nl >> 3) << 9) + rowg * 8 + (nl & 7); };

  auto cvt8 = [&](const float* p) -> short8 {
    float4 f0 = *(const float4*)p, f1 = *(const float4*)(p + 4);
    short8 r;
    r[0] = (short)f2bf(f0.x); r[1] = (short)f2bf(f0.y);
    r[2] = (short)f2bf(f0.z); r[3] = (short)f2bf(f0.w);
    r[4] = (short)f2bf(f1.x); r[5] = (short)f2bf(f1.y);
    r[6] = (short)f2bf(f1.z); r[7] = (short)f2bf(f1.w);
    return r;
  };

  // fused poll: lane's 16 A-fragments (dwordx4 each) + optional guard dword.
  // frag t = image dwords [(t*4+q)*64 + m*4 .. +3]  (byte off t*1024+q*256+m*16)
  auto pollfrag = [&](const u32* dslot, const u32* gp, bool gon, uint4* hv) {
    const char* bp = (const char*)dslot + q * 256 + m * 16;
    int it = 0;
    for (;;) {
      #pragma unroll
      for (int tg = 0; tg < 4; ++tg) {
        const char* p = bp + tg * 4096;
        hv[tg*4+0] = ldx4_o0(p); hv[tg*4+1] = ldx4_o1(p);
        hv[tg*4+2] = ldx4_o2(p); hv[tg*4+3] = ldx4_o3(p);
      }
      u32 gv = 0;
      if (gon) gv = __hip_atomic_load(gp, __ATOMIC_RELAXED, AGENT_SCOPE);
      asm volatile("s_waitcnt vmcnt(0)" ::: "memory");
      __builtin_amdgcn_sched_barrier(0);
      u32 mx = 0;
      #pragma unroll
      for (int t = 0; t < 16; ++t)
        mx = um(um(hv[t].x, hv[t].y), um(um(hv[t].z, hv[t].w), mx));
      bool ok = (mx != SENT) && (!gon || (gv != SENT));
      if (__all(ok)) break;
      if (++it >= POLL_CAP) break;
    }
  };

  // in-wave act: gates via shfl_xor(8) (C layout col=lane&15,row=(lane>>4)*4+r);
  // lanes n<8 handle rows r=0,1; n>=8 handle r=2,3. c-state in regs.
  auto act_emit = [&](f32x4 a0, f32x4 a1, float& cA, float& cB, u32* dst) {
    f32x4 o0, o1;
    #pragma unroll
    for (int r = 0; r < 4; ++r) { o0[r] = __shfl_xor(a0[r], 8); o1[r] = __shfl_xor(a1[r], 8); }
    const bool hi = (lane & 8) != 0;
    u32 hb[2];
    #pragma unroll
    for (int j = 0; j < 2; ++j) {
      int r = (hi ? 2 : 0) + j;
      float gi = hi ? o0[r] : a0[r];
      float gf = hi ? a0[r] : o0[r];
      float gg = hi ? o1[r] : a1[r];
      float go = hi ? a1[r] : o1[r];
      float c  = j ? cB : cA;
      c = sigm(gf) * c + sigm(gi) * tanha(gg);
      if (j) cB = c; else cA = c;
      hb[j] = f2bf(sigm(go) * tanha(c));
    }
    u32 p0 = __shfl_xor(hb[0], 1), p1 = __shfl_xor(hb[1], 1);
    wait_vm0();                       // clears (and older) drained before data
    if (!(lane & 1)) {
      int b0 = 4 * q + (hi ? 2 : 0), dw = (lane & 7) >> 1;
      __hip_atomic_store(dst + b0 * 4 + dw,       hb[0] | (p0 << 16),
                         __ATOMIC_RELAXED, AGENT_SCOPE);
      __hip_atomic_store(dst + (b0 + 1) * 4 + dw, hb[1] | (p1 << 16),
                         __ATOMIC_RELAXED, AGENT_SCOPE);
    }
  };

  auto gbar = [&](u32 target) {
    __syncthreads();
    if (tid == 0) {
      __hip_atomic_fetch_add(gcnt, 1u, __ATOMIC_RELEASE, AGENT_SCOPE);
      int it = 0;
      while (__hip_atomic_load(gcnt, __ATOMIC_RELAXED, AGENT_SCOPE) < target && ++it < SPIN_CAP) {}
      (void)__hip_atomic_load(gcnt, __ATOMIC_ACQUIRE, AGENT_SCOPE);
    }
    __syncthreads();
  };

  short8 wb[32];
  short8 xw0[4], xw1[4];
  float bA = 0.f, bB = 0.f;

  if (tid < 2) sFlag[tid] = 0;

  // ===== encoder weights/biases -> VGPRs (per wave) =====
  if (wid == 0) {
    #pragma unroll
    for (int t = 0; t < 4; ++t) {
      xw0[t] = cvt8(eWih0 + (size_t)gwr(m) * 128 + t * 32 + qo);
      xw1[t] = cvt8(eWih0 + (size_t)gwr(16 + m) * 128 + t * 32 + qo);
    }
    #pragma unroll
    for (int t = 0; t < 16; ++t) {
      wb[t]      = cvt8(eWhh0 + (size_t)gwr(m) * 512 + t * 32 + qo);
      wb[16 + t] = cvt8(eWhh0 + (size_t)gwr(16 + m) * 512 + t * 32 + qo);
    }
    bA = ebi0[gwr(m)] + ebh0[gwr(m)];
    bB = ebi0[gwr(16 + m)] + ebh0[gwr(16 + m)];
  } else if (wid == 1) {
    #pragma unroll
    for (int t = 0; t < 16; ++t) {
      wb[t]      = cvt8(eWih1 + (size_t)gwr(m) * 512 + t * 32 + qo);
      wb[16 + t] = cvt8(eWih1 + (size_t)gwr(16 + m) * 512 + t * 32 + qo);
    }
    bA = ebi1[gwr(m)] + ebh1[gwr(m)];
    bB = ebi1[gwr(16 + m)] + ebh1[gwr(16 + m)];
  } else {
    #pragma unroll
    for (int t = 0; t < 16; ++t) {
      wb[t]      = cvt8(eWhh1 + (size_t)gwr(m) * 512 + t * 32 + qo);
      wb[16 + t] = cvt8(eWhh1 + (size_t)gwr(16 + m) * 512 + t * 32 + qo);
    }
  }
  __syncthreads();

  // ===================== encoder =====================
  if (wid == 0) {
    float c0 = 0.f, c1 = 0.f;
    const float* xb = x + (size_t)(col * 16 + m) * 131072;
    float4 xf[8];
    #pragma unroll
    for (int t = 0; t < 4; ++t) {
      xf[2*t]   = *(const float4*)(xb + t * 32 + qo);
      xf[2*t+1] = *(const float4*)(xb + t * 32 + qo + 4);
    }
    for (int s = 0; s < 1024; ++s) {
      f32x4 a0 = {bA, bA, bA, bA}, a1 = {bB, bB, bB, bB};
      #pragma unroll
      for (int t = 0; t < 4; ++t) {     // x part: off critical path
        float4 f0 = xf[2*t], f1 = xf[2*t+1];
        short8 xa;
        xa[0]=(short)f2bf(f0.x); xa[1]=(short)f2bf(f0.y);
        xa[2]=(short)f2bf(f0.z); xa[3]=(short)f2bf(f0.w);
        xa[4]=(short)f2bf(f1.x); xa[5]=(short)f2bf(f1.y);
        xa[6]=(short)f2bf(f1.z); xa[7]=(short)f2bf(f1.w);
        a0 = __builtin_amdgcn_mfma_f32_16x16x32_bf16(xa, xw0[t], a0, 0, 0, 0);
        a1 = __builtin_amdgcn_mfma_f32_16x16x32_bf16(xa, xw1[t], a1, 0, 0, 0);
      }
      uint4 hv[16];
      pollfrag(h0r + (((s + 2) % 3) * 4 + col) * 4096,
               h1r + (((s + 1) % 3) * 4 + col) * 4096 + (lane << 6),
               s >= 2, hv);
      __hip_atomic_store(h0r + (((s + 1) % 3) * 4 + col) * 4096 + (rowg << 6) + lane,
                         SENT, __ATOMIC_RELAXED, AGENT_SCOPE);
      #pragma unroll
      for (int t = 0; t < 16; ++t) {
        short8 a = as_s8(hv[t]);
        a0 = __builtin_amdgcn_mfma_f32_16x16x32_bf16(a, wb[t],      a0, 0, 0, 0);
        a1 = __builtin_amdgcn_mfma_f32_16x16x32_bf16(a, wb[16 + t], a1, 0, 0, 0);
      }
      act_emit(a0, a1, c0, c1, h0r + ((s % 3) * 4 + col) * 4096 + (rowg << 6));
      {  // prefetch x[s+1] (overlaps next poll; covered by its vmcnt(0))
        const float* xp = xb + (size_t)((s + 1 < 1024) ? s + 1 : 1023) * 128;
        #pragma unroll
        for (int t = 0; t < 4; ++t) {
          xf[2*t]   = *(const float4*)(xp + t * 32 + qo);
          xf[2*t+1] = *(const float4*)(xp + t * 32 + qo + 4);
        }
      }
    }
  } else if (wid == 1) {
    float c0 = 0.f, c1 = 0.f;
    for (int s = 1; s <= 1024; ++s) {
      f32x4 a0 = {bA, bA, bA, bA}, a1 = {bB, bB, bB, bB};
      uint4 hv[16];
      pollfrag(h0r + (((s + 2) % 3) * 4 + col) * 4096,
               h1r + (((s + 1) % 3) * 4 + col) * 4096 + (lane << 6),
               s >= 2, hv);
      __hip_atomic_store(h1r + ((s % 3) * 4 + col) * 4096 + (rowg << 6) + lane,
                         SENT, __ATOMIC_RELAXED, AGENT_SCOPE);
      #pragma unroll
      for (int t = 0; t < 16; ++t) {
        short8 a = as_s8(hv[t]);
        a0 = __builtin_amdgcn_mfma_f32_16x16x32_bf16(a, wb[t],      a0, 0, 0, 0);
        a1 = __builtin_amdgcn_mfma_f32_16x16x32_bf16(a, wb[16 + t], a1, 0, 0, 0);
      }
      {  // merge wave2 partials (Whh1 half)
        int p = s & 1, it = 0;
        while (__hip_atomic_load(&sFlag[p], __ATOMIC_ACQUIRE, WG_SCOPE) != s
               && ++it < SPIN_CAP) {}
        #pragma unroll
        for (int r = 0; r < 4; ++r) {
          a0[r] += sP2[p][0][lane * 4 + r];
          a1[r] += sP2[p][1][lane * 4 + r];
        }
      }
      act_emit(a0, a1, c0, c1, h1r + (((s - 1) % 3) * 4 + col) * 4096 + (rowg << 6));
    }
  } else {
    for (int s = 1; s <= 1024; ++s) {
      uint4 hv[16];
      pollfrag(h1r + (((s + 1) % 3) * 4 + col) * 4096, nullptr, false, hv);
      f32x4 a0 = {0.f, 0.f, 0.f, 0.f}, a1 = {0.f, 0.f, 0.f, 0.f};
      #pragma unroll
      for (int t = 0; t < 16; ++t) {
        short8 a = as_s8(hv[t]);
        a0 = __builtin_amdgcn_mfma_f32_16x16x32_bf16(a, wb[t],      a0, 0, 0, 0);
        a1 = __builtin_amdgcn_mfma_f32_16x16x32_bf16(a, wb[16 + t], a1, 0, 0, 0);
      }
      int p = s & 1;
      #pragma unroll
      for (int r = 0; r < 4; ++r) {
        sP2[p][0][lane * 4 + r] = a0[r];
        sP2[p][1][lane * 4 + r] = a1[r];
      }
      __hip_atomic_store(&sFlag[p], s, __ATOMIC_RELEASE, WG_SCOPE);
    }
  }
  __syncthreads();

  // ================= latent: z = h1[1023] @ tlW^T + tlb ====================
  if (tid < 128) {   // h1[1023] in slot 0
    const u32* b1 = h1r + (0 * 4 + col) * 4096 + tid;
    u32 v1[32];
    int it = 0; bool ok = false;
    while (!ok && it++ < POLL_CAP) {
      ok = true;
      #pragma unroll
      for (int i = 0; i < 32; ++i) {
        v1[i] = __hip_atomic_load(b1 + i * 128, __ATOMIC_RELAXED, AGENT_SCOPE);
        ok &= (v1[i] != SENT);
      }
    }
    u32* dH1 = (u32*)sH1z;
    #pragma unroll
    for (int i = 0; i < 32; ++i) {
      int g = i * 128 + tid;
      dH1[((g >> 2) & 15) * 260 + (g >> 6) * 4 + (g & 3)] = v1[i];
    }
  }
  __syncthreads();
  if (tid < 16) {
    int b = tid;
    float acc = tlb[rowg];
    for (int kk = 0; kk < 512; kk += 8) {
      short8 hv = *(const short8*)(sH1z + b * 520 + kk);
      #pragma unroll
      for (int j = 0; j < 8; ++j) acc += bf2f((u16)hv[j]) * tlW[rowg * 512 + kk + j];
    }
    int gb = col * 16 + b;
    __hip_atomic_store((u32*)zbuf + gb * 64 + rowg, __float_as_uint(acc),
                       __ATOMIC_RELAXED, AGENT_SCOPE);
    out[8388608 + gb * 64 + rowg] = acc;
  }
  gbar(256);        // z visible; all WGs past encoder ring reads

  // ================= decoder weights -> VGPRs ==============================
  short8 rcw[16]; float opbv = 0.f;
  if (wid == 0) {
    #pragma unroll
    for (int t = 0; t < 16; ++t) {
      wb[t]      = cvt8(dWhh0 + (size_t)gwr(m) * 512 + t * 32 + qo);
      wb[16 + t] = cvt8(dWhh0 + (size_t)gwr(16 + m) * 512 + t * 32 + qo);
    }
    bA = dbi0[gwr(m)] + dbh0[gwr(m)];
    bB = dbi0[gwr(16 + m)] + dbh0[gwr(16 + m)];
  } else if (wid == 1) {
    #pragma unroll
    for (int t = 0; t < 16; ++t) {
      wb[t]      = cvt8(dWih1 + (size_t)gwr(m) * 512 + t * 32 + qo);
      wb[16 + t] = cvt8(dWih1 + (size_t)gwr(16 + m) * 512 + t * 32 + qo);
    }
    bA = dbi1[gwr(m)] + dbh1[gwr(m)];
    bB = dbi1[gwr(16 + m)] + dbh1[gwr(16 + m)];
  } else {
    #pragma unroll
    for (int t = 0; t < 16; ++t) {
      wb[t]      = cvt8(dWhh1 + (size_t)gwr(m) * 512 + t * 32 + qo);
      wb[16 + t] = cvt8(dWhh1 + (size_t)gwr(16 + m) * 512 + t * 32 + qo);
    }
    const short8 z8 = {0, 0, 0, 0, 0, 0, 0, 0};
    #pragma unroll
    for (int t = 0; t < 16; ++t) rcw[t] = z8;
    if (m < 2) {
      #pragma unroll
      for (int t = 0; t < 16; ++t)
        rcw[t] = cvt8(opW + (size_t)(rowg * 2 + m) * 512 + t * 32 + qo);
      opbv = opb[rowg * 2 + m];
    }
  }

  // ---- reset rings (all 3 slots SENT, own blocks; 192 thr = 3x64) ----
  {
    int slot = tid >> 6, d = tid & 63;
    __hip_atomic_store(h0r + (slot * 4 + col) * 4096 + (rowg << 6) + d, SENT,
                       __ATOMIC_RELAXED, AGENT_SCOPE);
    __hip_atomic_store(h1r + (slot * 4 + col) * 4096 + (rowg << 6) + d, SENT,
                       __ATOMIC_RELAXED, AGENT_SCOPE);
  }
  if (tid < 128) {   // stage z rows for init_h
    int ri = tid >> 3, kk = (tid & 7) * 8;
    int zr = ((ri >> 3) << 5) + 8 * col + (ri & 7);
    #pragma unroll
    for (int j = 0; j < 8; ++j)
      sZ[ri * 64 + kk + j] = __uint_as_float(
          __hip_atomic_load((u32*)zbuf + zr * 64 + kk + j, __ATOMIC_RELAXED, AGENT_SCOPE));
  }
  wait_vm0();        // resets drained before init_h data stores
  __syncthreads();

  // ---- init_h = tanh(z @ lhW^T + lhb) -> h[-1] data into slot 2 ----
  if (tid < 128) {
    int hh = (tid >> 4) & 7, qb = (tid >> 3) & 1, u = tid & 7;
    #pragma unroll
    for (int li = 0; li < 2; ++li) {
      int cc = qb * 512 + rowg * 8 + u;
      int bl = 2 * hh + qb;
      float acc2 = lhb[cc];
      const float* lw = lhW + (size_t)cc * 64;
      #pragma unroll 8
      for (int k = 0; k < 64; ++k) acc2 += sZ[(li * 8 + hh) * 64 + k] * lw[k];
      u16 hb = f2bf(tanha(acc2));
      u32 other = __shfl_xor((u32)hb, 1);
      if (!(u & 1)) {
        u32 v = (u32)hb | (other << 16);
        u32* ring = li ? h1r : h0r;
        __hip_atomic_store(ring + (2 * 4 + col) * 4096 + (rowg << 6) + bl * 4 + (u >> 1),
                           v, __ATOMIC_RELAXED, AGENT_SCOPE);
      }
    }
  }
  wait_vm0();
  gbar(512);         // resets + init data globally visible before decoder polls

  // ===================== decoder =====================
  if (wid == 0) {
    float c0 = 0.f, c1 = 0.f;
    for (int s = 0; s < 1024; ++s) {
      f32x4 a0 = {bA, bA, bA, bA}, a1 = {bB, bB, bB, bB};
      uint4 hv[16];
      pollfrag(h0r + (((s + 2) % 3) * 4 + col) * 4096,
               h1r + (((s + 1) % 3) * 4 + col) * 4096 + (lane << 6),
               s >= 2, hv);
      __hip_atomic_store(h0r + (((s + 1) % 3) * 4 + col) * 4096 + (rowg << 6) + lane,
                         SENT, __ATOMIC_RELAXED, AGENT_SCOPE);
      #pragma unroll
      for (int t = 0; t < 16; ++t) {
        short8 a = as_s8(hv[t]);
        a0 = __builtin_amdgcn_mfma_f32_16x16x32_bf16(a, wb[t],      a0, 0, 0, 0);
        a1 = __builtin_amdgcn_mfma_f32_16x16x32_bf16(a, wb[16 + t], a1, 0, 0, 0);
      }
      act_emit(a0, a1, c0, c1, h0r + ((s % 3) * 4 + col) * 4096 + (rowg << 6));
    }
  } else if (wid == 1) {
    float c0 = 0.f, c1 = 0.f;
    for (int s = 1; s <= 1024; ++s) {
      f32x4 a0 = {bA, bA, bA, bA}, a1 = {bB, bB, bB, bB};
      uint4 hv[16];
      pollfrag(h0r + (((s + 2) % 3) * 4 + col) * 4096,
               h1r + (((s + 1) % 3) * 4 + col) * 4096 + (lane << 6),
               s >= 2, hv);
      __hip_atomic_store(h1r + ((s % 3) * 4 + col) * 4096 + (rowg << 6) + lane,
                         SENT, __ATOMIC_RELAXED, AGENT_SCOPE);
      #pragma unroll
      for (int t = 0; t < 16; ++t) {
        short8 a = as_s8(hv[t]);
        a0 = __builtin_amdgcn_mfma_f32_16x16x32_bf16(a, wb[t],      a0, 0, 0, 0);
        a1 = __builtin_amdgcn_mfma_f32_16x16x32_bf16(a, wb[16 + t], a1, 0, 0, 0);
      }
      {
        int p = s & 1, it = 0;
        while (__hip_atomic_load(&sFlag[p], __ATOMIC_ACQUIRE, WG_SCOPE) != 3000 + s
               && ++it < SPIN_CAP) {}
        #pragma unroll
        for (int r = 0; r < 4; ++r) {
          a0[r] += sP2[p][0][lane * 4 + r];
          a1[r] += sP2[p][1][lane * 4 + r];
        }
      }
      act_emit(a0, a1, c0, c1, h1r + (((s - 1) % 3) * 4 + col) * 4096 + (rowg << 6));
    }
  } else {
    for (int s = 1; s <= 1024; ++s) {
      uint4 hv[16];
      pollfrag(h1r + (((s + 1) % 3) * 4 + col) * 4096, nullptr, false, hv);
      f32x4 a0 = {0.f, 0.f, 0.f, 0.f}, a1 = {0.f, 0.f, 0.f, 0.f};
      #pragma unroll
      for (int t = 0; t < 16; ++t) {
        short8 a = as_s8(hv[t]);
        a0 = __builtin_amdgcn_mfma_f32_16x16x32_bf16(a, wb[t],      a0, 0, 0, 0);
        a1 = __builtin_amdgcn_mfma_f32_16x16x32_bf16(a, wb[16 + t], a1, 0, 0, 0);
      }
      int p = s & 1;
      #pragma unroll
      for (int r = 0; r < 4; ++r) {
        sP2[p][0][lane * 4 + r] = a0[r];
        sP2[p][1][lane * 4 + r] = a1[r];
      }
      __hip_atomic_store(&sFlag[p], 3000 + s, __ATOMIC_RELEASE, WG_SCOPE);
      if (s >= 2) {   // recon t = s-2 on already-loaded h1 frags
        f32x4 rc = {0.f, 0.f, 0.f, 0.f};
        #pragma unroll
        for (int t = 0; t < 16; ++t)
          rc = __builtin_amdgcn_mfma_f32_16x16x32_bf16(as_s8(hv[t]), rcw[t], rc, 0, 0, 0);
        if (m < 2) {
          #pragma unroll
          for (int r = 0; r < 4; ++r)
            out[(size_t)(col * 16 + q * 4 + r) * 131072 + (size_t)(s - 2) * 128
                + rowg * 2 + m] = sigm(rc[r] + opbv);
        }
      }
    }
    {  // tail recon t=1023: h1dec[1023] in slot 0
      uint4 hv[16];
      pollfrag(h1r + (0 * 4 + col) * 4096, nullptr, false, hv);
      f32x4 rc = {0.f, 0.f, 0.f, 0.f};
      #pragma unroll
      for (int t = 0; t < 16; ++t)
        rc = __builtin_amdgcn_mfma_f32_16x16x32_bf16(as_s8(hv[t]), rcw[t], rc, 0, 0, 0);
      if (m < 2) {
        #pragma unroll
        for (int r = 0; r < 4; ++r)
          out[(size_t)(col * 16 + q * 4 + r) * 131072 + (size_t)1023 * 128
              + rowg * 2 + m] = sigm(rc[r] + opbv);
      }
    }
  }
}

extern "C" void kernel_launch(void* const* d_in, const int* in_sizes, int n_in,
                              void* d_out, int out_size, void* d_ws, size_t ws_size,
                              hipStream_t stream) {
  (void)in_sizes; (void)n_in; (void)out_size; (void)ws_size;
  char* ws = (char*)d_ws;
  // control + zbuf
  hipMemsetAsync(ws, 0, 32768, stream);
  // h0 ring: q0,q1 = SENT, q2 = 0.0 data (h0[-1] = 0)
  hipMemsetAsync(ws + 32768, 0xFF, 131072, stream);
  hipMemsetAsync(ws + 163840, 0x00, 65536, stream);
  // h1 ring: q0,q1 = SENT, q2 = 0.0 data (h1[-1] = 0)
  hipMemsetAsync(ws + 229376, 0xFF, 131072, stream);
  hipMemsetAsync(ws + 360448, 0x00, 65536, stream);
  lstm_ae_kernel<<<dim3(256), dim3(192), 0, stream>>>(
      (const float*)d_in[0],
      (const float*)d_in[1],  (const float*)d_in[2],
      (const float*)d_in[3],  (const float*)d_in[4],
      (const float*)d_in[5],  (const float*)d_in[6],
      (const float*)d_in[7],  (const float*)d_in[8],
      (const float*)d_in[10],
      (const float*)d_in[11], (const float*)d_in[12],
      (const float*)d_in[13], (const float*)d_in[14],
      (const float*)d_in[15], (const float*)d_in[16],
      (const float*)d_in[17], (const float*)d_in[18],
      (const float*)d_in[19], (const float*)d_in[20],
      (const float*)d_in[21], (const float*)d_in[22],
      (float*)d_out, (char*)d_ws);
}

// Round 4
// 5209.369 us; speedup vs baseline: 1.8151x; 1.8151x over previous
//
#include <hip/hip_runtime.h>
#include <cstdint>
#include <cstddef>

typedef unsigned short u16;
typedef unsigned int u32;
typedef __attribute__((ext_vector_type(8))) short short8;
typedef __attribute__((ext_vector_type(4))) float f32x4;

#define AGENT_SCOPE __HIP_MEMORY_SCOPE_AGENT
#define SPIN_CAP 20000000
#define POLL_CAP 200000
#define SENT 0xFFFFFFFFu

__device__ __forceinline__ u16 f2bf(float f) {
  u32 u = __float_as_uint(f);
  return (u16)((u + 0x7FFFu + ((u >> 16) & 1u)) >> 16);
}
__device__ __forceinline__ float bf2f(u16 s) { return __uint_as_float(((u32)s) << 16); }
__device__ __forceinline__ float sigm(float x) { return 1.f / (1.f + __expf(-x)); }
__device__ __forceinline__ float tanha(float x) { return 1.f - 2.f / (__expf(2.f * x) + 1.f); }
__device__ __forceinline__ void wait_vm0() { asm volatile("s_waitcnt vmcnt(0)" ::: "memory"); }
__device__ __forceinline__ u32 um(u32 a, u32 b) { return a > b ? a : b; }

// cache-bypassing agent-visible 16B load (R3-verified semantics)
__device__ __forceinline__ uint4 ldx4(const void* p) {
  uint4 r;
  asm volatile("global_load_dwordx4 %0, %1, off sc0 sc1" : "=v"(r) : "v"(p) : "memory");
  return r;
}

// Barrier-free persistent LSTM autoencoder — R0 structure (best known), with
// the poll de-contention package as the ONLY change:
//   (a) dwordx4 poll loads (1/4 request count, same bytes),
//   (b) sticky per-ring done (h1 has 2-step slack -> stop re-loading once seen),
//   (c) s_sleep(4) backoff between poll iterations.
// 256 WGs x 256 thr: col = bid&3 (16 batches), rowg = bid>>2 in [0,64) (8 hidden
// units = 32 gate rows). h exchange via depth-3 LLC ring, bf16 pairs packed in
// dwords; consumers poll the DATA dwords (fused detect+transfer, single RTT)
// until != SENT; producers SENT-clear the buffer reused at slot s+1 (safe:
// completing stage of h[s-1] implies all WGs staged h[s-2]; act's vmcnt(0)
// orders clears before the next slot's data stores). No flags, no RMW.
__global__ void __launch_bounds__(256, 1)
lstm_ae_kernel(const float* __restrict__ x,
    const float* __restrict__ eWih0, const float* __restrict__ eWhh0,
    const float* __restrict__ ebi0,  const float* __restrict__ ebh0,
    const float* __restrict__ eWih1, const float* __restrict__ eWhh1,
    const float* __restrict__ ebi1,  const float* __restrict__ ebh1,
    const float* __restrict__ dWhh0,
    const float* __restrict__ dbi0,  const float* __restrict__ dbh0,
    const float* __restrict__ dWih1, const float* __restrict__ dWhh1,
    const float* __restrict__ dbi1,  const float* __restrict__ dbh1,
    const float* __restrict__ tlW,   const float* __restrict__ tlb,
    const float* __restrict__ lhW,   const float* __restrict__ lhb,
    const float* __restrict__ opW,   const float* __restrict__ opb,
    float* __restrict__ out, char* __restrict__ wsb)
{
  __shared__ __align__(16) u16 sH0[16 * 520];   // staged h0 bf16, row stride 520
  __shared__ __align__(16) u16 sH1[16 * 520];
  __shared__ __align__(16) u16 sX[16 * 136];
  __shared__ __align__(16) u16 sOPW[2 * 520];
  __shared__ float sP[4 * 256];                  // per-wave MFMA partials [16b][16n]
  __shared__ float sBias[64];                    // [2 layer][32 gate-rows]
  __shared__ float sC[256];                      // [2][16 b][8 u] cell state fp32
  __shared__ float sZ[16 * 64];
  __shared__ float sOPB[4];

  u32* gcnt  = (u32*)wsb;
  float* zbuf= (float*)(wsb + 4096);             // [64][64]
  u32* h0r   = (u32*)(wsb + 32768);              // [3 q][4 col][64 rowg][64 dw]
  u32* h1r   = (u32*)(wsb + 229376);             // same (196608 B each)

  const int tid  = threadIdx.x;
  const int col  = blockIdx.x & 3;
  const int rowg = blockIdx.x >> 2;              // 0..63
  const int wid  = tid >> 6;
  const int lane = tid & 63;
  const int m    = lane & 15;
  const int qo   = (lane >> 4) * 8;

  // ---------- helpers ----------
  // poll+stage one slot's h0 (q0) and optionally h1 (q1) column images into LDS.
  // Vectorized (x4) fused detect+transfer with sticky per-ring done + backoff.
  auto stage_slot = [&](int q0, int q1, bool p0on, bool p1on) {
    const char* base0 = (const char*)(h0r + ((q0 * 4 + col) << 12)) + tid * 16;
    const char* base1 = (const char*)(h1r + ((q1 * 4 + col) << 12)) + tid * 16;
    uint4 v0[4], v1[4];
    bool d0 = !p0on, d1 = !p1on;
    int it = 0;
    for (;;) {
      if (!d0) {
        #pragma unroll
        for (int i = 0; i < 4; ++i) v0[i] = ldx4(base0 + i * 4096);
      }
      if (!d1) {
        #pragma unroll
        for (int i = 0; i < 4; ++i) v1[i] = ldx4(base1 + i * 4096);
      }
      asm volatile("s_waitcnt vmcnt(0)" ::: "memory");
      __builtin_amdgcn_sched_barrier(0);
      if (!d0) {
        u32 mx = 0;
        #pragma unroll
        for (int i = 0; i < 4; ++i)
          mx = um(mx, um(um(v0[i].x, v0[i].y), um(v0[i].z, v0[i].w)));
        d0 = (mx != SENT);
      }
      if (!d1) {
        u32 mx = 0;
        #pragma unroll
        for (int i = 0; i < 4; ++i)
          mx = um(mx, um(um(v1[i].x, v1[i].y), um(v1[i].z, v1[i].w)));
        d1 = (mx != SENT);
      }
      if ((d0 && d1) || ++it >= POLL_CAP) break;
      __builtin_amdgcn_s_sleep(4);
    }
    // LDS scatter: dword g = i*1024 + tid*4 + j  ->  b=(tid&15), rg=i*16+(tid>>4)
    u32* dH0 = (u32*)sH0; u32* dH1 = (u32*)sH1;
    const int db = (tid & 15) * 260 + (tid >> 4) * 4;
    if (p0on) {
      #pragma unroll
      for (int i = 0; i < 4; ++i) *(uint4*)(dH0 + db + i * 64) = v0[i];
    }
    if (p1on) {
      #pragma unroll
      for (int i = 0; i < 4; ++i) *(uint4*)(dH1 + db + i * 64) = v1[i];
    }
  };

  // SENT-clear own blocks of the buffers reused at slot s+1 (issued during compute;
  // drained by act's wait_vm0, i.e. before this slot's data stores land)
  auto clears = [&](int s) {
    if (tid < 64) {
      int cq0 = (s + 1) % 3, cq1 = s % 3;
      __hip_atomic_store(h0r + ((cq0 * 4 + col) << 12) + (rowg << 6) + tid,
                         SENT, __ATOMIC_RELAXED, AGENT_SCOPE);
      __hip_atomic_store(h1r + ((cq1 * 4 + col) << 12) + (rowg << 6) + tid,
                         SENT, __ATOMIC_RELAXED, AGENT_SCOPE);
    }
  };

  auto stage_xt = [&](int s) {
    int b = tid >> 4, seg = tid & 15;
    const float* p = x + (size_t)(col * 16 + b) * 131072 + (size_t)s * 128 + seg * 8;
    float4 f0 = *(const float4*)p, f1 = *(const float4*)(p + 4);
    uint4 v;
    v.x = (u32)f2bf(f0.x) | ((u32)f2bf(f0.y) << 16);
    v.y = (u32)f2bf(f0.z) | ((u32)f2bf(f0.w) << 16);
    v.z = (u32)f2bf(f1.x) | ((u32)f2bf(f1.y) << 16);
    v.w = (u32)f2bf(f1.z) | ((u32)f2bf(f1.w) << 16);
    *(uint4*)(sX + b * 136 + seg * 8) = v;
  };

  // B-fragment loader: weight row, bf16-converted, k window kofs+qo..+8
  auto ldw = [&](const float* W, int ld, int row, int kofs) -> short8 {
    const float* p = W + (size_t)row * ld + kofs + qo;
    float4 f0 = *(const float4*)p, f1 = *(const float4*)(p + 4);
    short8 r;
    r[0] = (short)f2bf(f0.x); r[1] = (short)f2bf(f0.y);
    r[2] = (short)f2bf(f0.z); r[3] = (short)f2bf(f0.w);
    r[4] = (short)f2bf(f1.x); r[5] = (short)f2bf(f1.y);
    r[6] = (short)f2bf(f1.z); r[7] = (short)f2bf(f1.w);
    return r;
  };

  // gates (R2-verified mapping): L0 slots 0,1; L1 slots 2,3.
  auto act_store = [&](bool L0a, bool L1a, int q0, int q1) {
    int li = tid >> 7, b = (tid >> 3) & 15, u = tid & 7;
    bool actv = li ? L1a : L0a;
    float hv = 0.f;
    if (actv) {
      float gi = sP[(li*2)*256   + b*16 + u]     + sBias[li*32 + u];
      float gf = sP[(li*2)*256   + b*16 + 8 + u] + sBias[li*32 + 8 + u];
      float gg = sP[(li*2+1)*256 + b*16 + u]     + sBias[li*32 + 16 + u];
      float go = sP[(li*2+1)*256 + b*16 + 8 + u] + sBias[li*32 + 24 + u];
      float c = sC[(li*16 + b)*8 + u];
      c = sigm(gf)*c + sigm(gi)*tanha(gg);
      sC[(li*16 + b)*8 + u] = c;
      hv = sigm(go)*tanha(c);
    }
    u16 hb = f2bf(hv);
    u32 other = __shfl_xor((u32)hb, 1);
    if (actv && !(u & 1)) {
      u32 v = (u32)hb | (other << 16);
      u32* ring = li ? h1r : h0r;
      int q = li ? q1 : q0;
      __hip_atomic_store(ring + ((q * 4 + col) << 12) + (rowg << 6) + b * 4 + (u >> 1),
                         v, __ATOMIC_RELAXED, AGENT_SCOPE);
    }
  };

  auto gbar = [&](u32 target) {
    __syncthreads();
    if (tid == 0) {
      __hip_atomic_fetch_add(gcnt, 1u, __ATOMIC_RELEASE, AGENT_SCOPE);
      int it = 0;
      while (__hip_atomic_load(gcnt, __ATOMIC_RELAXED, AGENT_SCOPE) < target && ++it < SPIN_CAP) {}
      (void)__hip_atomic_load(gcnt, __ATOMIC_ACQUIRE, AGENT_SCOPE);
    }
    __syncthreads();
  };

  // lane's weight row: n = (wid&1)*16 + m; gate = n>>3, unit = n&7
  const int nl = (wid & 1) * 16 + m;
  const int gw = ((nl >> 3) << 9) + rowg * 8 + (nl & 7);

  short8 wb[32];

  // ================= encoder weights -> VGPRs =================
  if (wid < 2) {
    #pragma unroll
    for (int t = 0; t < 4; ++t)  wb[t]      = ldw(eWih0, 128, gw, t * 32);
    #pragma unroll
    for (int t = 0; t < 16; ++t) wb[4 + t]  = ldw(eWhh0, 512, gw, t * 32);
  } else {
    #pragma unroll
    for (int t = 0; t < 16; ++t) wb[t]      = ldw(eWih1, 512, gw, t * 32);
    #pragma unroll
    for (int t = 0; t < 16; ++t) wb[16 + t] = ldw(eWhh1, 512, gw, t * 32);
  }
  if (tid < 64) {
    int li = tid >> 5, n = tid & 31;
    int g = ((n >> 3) << 9) + rowg * 8 + (n & 7);
    sBias[li * 32 + n] = li ? (ebi1[g] + ebh1[g]) : (ebi0[g] + ebh0[g]);
  }
  sC[tid] = 0.f;
  __syncthreads();

  // ================= encoder scan (lag-1 pipelined, barrier-free) =====
  for (int s = 0; s <= 1024; ++s) {
    const bool L0 = (s < 1024), L1 = (s >= 1);
    if (L0) stage_xt(s);
    stage_slot((s + 2) % 3, (s + 1) % 3, true, s >= 1);   // h0[s-1], h1[s-2]
    __syncthreads();
    clears(s);

    f32x4 acc = {0.f, 0.f, 0.f, 0.f};
    if (wid < 2) {
      if (L0) {
        #pragma unroll
        for (int t = 0; t < 4; ++t) {
          short8 a = *(const short8*)(sX + m * 136 + t * 32 + qo);
          acc = __builtin_amdgcn_mfma_f32_16x16x32_bf16(a, wb[t], acc, 0, 0, 0);
        }
        #pragma unroll
        for (int t = 0; t < 16; ++t) {
          short8 a = *(const short8*)(sH0 + m * 520 + t * 32 + qo);
          acc = __builtin_amdgcn_mfma_f32_16x16x32_bf16(a, wb[4 + t], acc, 0, 0, 0);
        }
      }
    } else {
      if (L1) {
        #pragma unroll
        for (int t = 0; t < 16; ++t) {
          short8 a = *(const short8*)(sH0 + m * 520 + t * 32 + qo);
          acc = __builtin_amdgcn_mfma_f32_16x16x32_bf16(a, wb[t], acc, 0, 0, 0);
        }
        #pragma unroll
        for (int t = 0; t < 16; ++t) {
          short8 a = *(const short8*)(sH1 + m * 520 + t * 32 + qo);
          acc = __builtin_amdgcn_mfma_f32_16x16x32_bf16(a, wb[16 + t], acc, 0, 0, 0);
        }
      }
    }
    {
      bool wact = (wid < 2) ? L0 : L1;
      if (wact) {
        int mb = (lane >> 4) * 4;
        #pragma unroll
        for (int r = 0; r < 4; ++r) sP[wid * 256 + (mb + r) * 16 + m] = acc[r];
      }
    }
    __syncthreads();                       // sP visible
    {
      // drain clears before data stores (act_store stores ring data)
      wait_vm0();
    }
    act_store(L0, L1, s % 3, (s + 2) % 3); // h0[s] -> q s%3, h1[s-1] -> q (s-1)%3
  }

  // ================= latent: z = h1[1023] @ tlW^T + tlb ====================
  {  // h1[1023] is in h1 ring q0 (stored at slot 1024)
    const u32* b1 = h1r + ((0 * 4 + col) << 12) + tid;
    u32 v1[16];
    int it = 0; bool ok = false;
    while (!ok && it++ < POLL_CAP) {
      ok = true;
      #pragma unroll
      for (int i = 0; i < 16; ++i) {
        v1[i] = __hip_atomic_load(b1 + i * 256, __ATOMIC_RELAXED, AGENT_SCOPE);
        ok &= (v1[i] != SENT);
      }
    }
    u32* dH1 = (u32*)sH1;
    #pragma unroll
    for (int i = 0; i < 16; ++i) {
      int g = i * 256 + tid;
      dH1[((g >> 2) & 15) * 260 + (g >> 6) * 4 + (g & 3)] = v1[i];
    }
  }
  __syncthreads();
  if (tid < 16) {
    int b = tid;
    float acc = tlb[rowg];
    for (int kk = 0; kk < 512; kk += 8) {
      short8 hv = *(const short8*)(sH1 + b * 520 + kk);
      #pragma unroll
      for (int j = 0; j < 8; ++j) acc += bf2f((u16)hv[j]) * tlW[rowg * 512 + kk + j];
    }
    int gb = col * 16 + b;
    __hip_atomic_store((u32*)zbuf + gb * 64 + rowg, __float_as_uint(acc),
                       __ATOMIC_RELAXED, AGENT_SCOPE);
    out[8388608 + gb * 64 + rowg] = acc;
  }
  gbar(256);        // z visible everywhere; all WGs done with encoder rings

  // ---- reset rings for decoder: all q SENT (own blocks) ----
  if (tid < 64) {
    #pragma unroll
    for (int q = 0; q < 3; ++q) {
      __hip_atomic_store(h0r + ((q * 4 + col) << 12) + (rowg << 6) + tid,
                         SENT, __ATOMIC_RELAXED, AGENT_SCOPE);
      __hip_atomic_store(h1r + ((q * 4 + col) << 12) + (rowg << 6) + tid,
                         SENT, __ATOMIC_RELAXED, AGENT_SCOPE);
    }
  }
  wait_vm0();       // clears committed before init_h data stores below

  // ================= decoder weights -> VGPRs ==============================
  if (wid < 2) {
    #pragma unroll
    for (int t = 0; t < 16; ++t) wb[t] = ldw(dWhh0, 512, gw, t * 32);
  } else {
    #pragma unroll
    for (int t = 0; t < 16; ++t) wb[t]      = ldw(dWih1, 512, gw, t * 32);
    #pragma unroll
    for (int t = 0; t < 16; ++t) wb[16 + t] = ldw(dWhh1, 512, gw, t * 32);
  }
  if (tid < 64) {
    int li = tid >> 5, n = tid & 31;
    int g = ((n >> 3) << 9) + rowg * 8 + (n & 7);
    sBias[li * 32 + n] = li ? (dbi1[g] + dbh1[g]) : (dbi0[g] + dbh0[g]);
  }
  for (int i = tid; i < 2 * 64; i += 256) {      // opW rows rowg*2, rowg*2+1
    int dd = i >> 6, k = (i & 63) * 8;
    const float* p = opW + (size_t)(rowg * 2 + dd) * 512 + k;
    float4 f0 = *(const float4*)p, f1 = *(const float4*)(p + 4);
    uint4 v;
    v.x = (u32)f2bf(f0.x) | ((u32)f2bf(f0.y) << 16);
    v.y = (u32)f2bf(f0.z) | ((u32)f2bf(f0.w) << 16);
    v.z = (u32)f2bf(f1.x) | ((u32)f2bf(f1.y) << 16);
    v.w = (u32)f2bf(f1.z) | ((u32)f2bf(f1.w) << 16);
    *(uint4*)(sOPW + dd * 520 + k) = v;
  }
  if (tid < 2) sOPB[tid] = opb[rowg * 2 + tid];
  sC[tid] = 0.f;

  // ---- init_h = tanh(z @ lhW^T + lhb), torch flat view (L,B,H):
  // init_h[l][bb][h] = M[l*32 + bb/2][(bb&1)*512 + h]; store as h[-1] into q2.
  {
    int ri = tid >> 4, kk = (tid & 15) * 4;
    int zr = ((ri >> 3) << 5) + 8 * col + (ri & 7);
    #pragma unroll
    for (int j = 0; j < 4; ++j)
      sZ[ri * 64 + kk + j] = __uint_as_float(
          __hip_atomic_load((u32*)zbuf + zr * 64 + kk + j, __ATOMIC_RELAXED, AGENT_SCOPE));
  }
  __syncthreads();
  {
    int li = tid >> 7, hh = (tid >> 4) & 7, qb = (tid >> 3) & 1, u = tid & 7;
    int cc = qb * 512 + rowg * 8 + u;
    int bl = 2 * hh + qb;
    float acc2 = lhb[cc];
    const float* lw = lhW + (size_t)cc * 64;
    #pragma unroll 8
    for (int k = 0; k < 64; ++k) acc2 += sZ[(li * 8 + hh) * 64 + k] * lw[k];
    u16 hb = f2bf(tanha(acc2));
    u32 other = __shfl_xor((u32)hb, 1);
    if (!(u & 1)) {
      u32 v = (u32)hb | (other << 16);
      u32* ring = li ? h1r : h0r;
      __hip_atomic_store(ring + ((2 * 4 + col) << 12) + (rowg << 6) + bl * 4 + (u >> 1),
                         v, __ATOMIC_RELAXED, AGENT_SCOPE);
    }
  }
  gbar(512);        // ring resets globally visible before any decoder poll

  // ================= decoder scan + fused recon ============================
  for (int s = 0; s <= 1025; ++s) {
    const bool L0 = (s < 1024), L1 = (s >= 1 && s <= 1024), RC = (s >= 2);
    stage_slot((s + 2) % 3, (s + 1) % 3, s <= 1024, s >= 1);
    __syncthreads();
    clears(s);

    f32x4 acc = {0.f, 0.f, 0.f, 0.f};
    if (wid < 2) {
      if (L0) {
        #pragma unroll
        for (int t = 0; t < 16; ++t) {
          short8 a = *(const short8*)(sH0 + m * 520 + t * 32 + qo);
          acc = __builtin_amdgcn_mfma_f32_16x16x32_bf16(a, wb[t], acc, 0, 0, 0);
        }
      }
    } else {
      if (L1) {
        #pragma unroll
        for (int t = 0; t < 16; ++t) {
          short8 a = *(const short8*)(sH0 + m * 520 + t * 32 + qo);
          acc = __builtin_amdgcn_mfma_f32_16x16x32_bf16(a, wb[t], acc, 0, 0, 0);
        }
        #pragma unroll
        for (int t = 0; t < 16; ++t) {
          short8 a = *(const short8*)(sH1 + m * 520 + t * 32 + qo);
          acc = __builtin_amdgcn_mfma_f32_16x16x32_bf16(a, wb[16 + t], acc, 0, 0, 0);
        }
      }
    }
    {
      bool wact = (wid < 2) ? L0 : L1;
      if (wact) {
        int mb = (lane >> 4) * 4;
        #pragma unroll
        for (int r = 0; r < 4; ++r) sP[wid * 256 + (mb + r) * 16 + m] = acc[r];
      }
    }
    __syncthreads();
    wait_vm0();                            // drains clears before data stores
    act_store(L0, L1, s % 3, (s + 2) % 3);

    if (RC) {   // recon[t=s-2] = sigmoid(h1dec[s-2] @ opW^T + opb), d = rowg*2+{0,1}
      __syncthreads();
      int b = tid >> 4, dd = (tid >> 3) & 1, pt = tid & 7;
      float acc2 = 0.f;
      int k0 = pt * 64;
      for (int kk = 0; kk < 64; kk += 8) {
        short8 hv = *(const short8*)(sH1 + b * 520 + k0 + kk);
        short8 wv = *(const short8*)(sOPW + dd * 520 + k0 + kk);
        #pragma unroll
        for (int j = 0; j < 8; ++j) acc2 += bf2f((u16)hv[j]) * bf2f((u16)wv[j]);
      }
      sP[tid] = acc2;
      __syncthreads();
      if (tid < 32) {
        int b2 = tid >> 1, d2 = tid & 1;
        float sum = sOPB[d2];
        #pragma unroll
        for (int j = 0; j < 8; ++j) sum += sP[b2 * 16 + d2 * 8 + j];
        out[(size_t)(col * 16 + b2) * 131072 + (size_t)(s - 2) * 128 + rowg * 2 + d2]
            = sigm(sum);
      }
    }
  }
}

extern "C" void kernel_launch(void* const* d_in, const int* in_sizes, int n_in,
                              void* d_out, int out_size, void* d_ws, size_t ws_size,
                              hipStream_t stream) {
  (void)in_sizes; (void)n_in; (void)out_size; (void)ws_size;
  char* ws = (char*)d_ws;
  // control + zbuf
  hipMemsetAsync(ws, 0, 32768, stream);
  // h0 ring: q0,q1 = SENT (not yet produced), q2 = 0.0 data (h0[-1] = 0)
  hipMemsetAsync(ws + 32768, 0xFF, 131072, stream);
  hipMemsetAsync(ws + 163840, 0x00, 65536, stream);
  // h1 ring: q0,q1 = SENT, q2 = 0.0 data (h1[-1] = 0)
  hipMemsetAsync(ws + 229376, 0xFF, 131072, stream);
  hipMemsetAsync(ws + 360448, 0x00, 65536, stream);
  lstm_ae_kernel<<<dim3(256), dim3(256), 0, stream>>>(
      (const float*)d_in[0],
      (const float*)d_in[1],  (const float*)d_in[2],
      (const float*)d_in[3],  (const float*)d_in[4],
      (const float*)d_in[5],  (const float*)d_in[6],
      (const float*)d_in[7],  (const float*)d_in[8],
      (const float*)d_in[10],
      (const float*)d_in[11], (const float*)d_in[12],
      (const float*)d_in[13], (const float*)d_in[14],
      (const float*)d_in[15], (const float*)d_in[16],
      (const float*)d_in[17], (const float*)d_in[18],
      (const float*)d_in[19], (const float*)d_in[20],
      (const float*)d_in[21], (const float*)d_in[22],
      (float*)d_out, (char*)d_ws);
}